// Round 1
// baseline (151.203 us; speedup 1.0000x reference)
//
#include <hip/hip_runtime.h>
#include <math.h>

#define SMOOTHING_F  0.2f
#define CONFIDENCE_F 0.8f

// Branch-free online logsumexp update: (m, s) <- combine with single x.
__device__ __forceinline__ void online_upd(float& m, float& s, float x) {
    float mn = fmaxf(m, x);
    s = s * __expf(m - mn) + __expf(x - mn);
    m = mn;
}

// Combine two (m, s) partial logsumexp states.
__device__ __forceinline__ void combine(float& m, float& s, float m2, float s2) {
    float mn = fmaxf(m, m2);
    s = s * __expf(m - mn) + s2 * __expf(m2 - mn);
    m = mn;
}

__global__ __launch_bounds__(256)
void row_loss_kernel(const float* __restrict__ pred,
                     const int* __restrict__ target,
                     float* __restrict__ row_loss,
                     int C) {
    const int row = blockIdx.x;
    const int tid = threadIdx.x;
    const float* p = pred + (size_t)row * (size_t)C;

    // Neutral element: use -FLT_MAX-ish (not -inf) so exp(m - mn) never sees NaN.
    float m = -3.0e38f;
    float s = 0.0f;

    // Row base is only 4B-aligned in general (C odd). Scalar lead-in to 16B.
    const int misalign = (int)(((size_t)row * (size_t)C) & 3);  // elements
    const int lead = (4 - misalign) & 3;

    const float4* vp = (const float4*)(p + lead);
    const int nv = (C - lead) >> 2;

    for (int v = tid; v < nv; v += 256) {
        float4 x = vp[v];
        online_upd(m, s, x.x);
        online_upd(m, s, x.y);
        online_upd(m, s, x.z);
        online_upd(m, s, x.w);
    }
    if (tid < lead) online_upd(m, s, p[tid]);
    const int tail_start = lead + (nv << 2);
    const int tail = C - tail_start;
    if (tid < tail) online_upd(m, s, p[tail_start + tid]);

    // Wave-64 butterfly combine.
    #pragma unroll
    for (int i = 1; i < 64; i <<= 1) {
        float m2 = __shfl_xor(m, i, 64);
        float s2 = __shfl_xor(s, i, 64);
        combine(m, s, m2, s2);
    }

    // Cross-wave combine (4 waves).
    __shared__ float sm[4], ss[4];
    const int wave = tid >> 6;
    if ((tid & 63) == 0) { sm[wave] = m; ss[wave] = s; }
    __syncthreads();

    if (tid == 0) {
        float M = sm[0], S = ss[0];
        #pragma unroll
        for (int w = 1; w < 4; ++w) combine(M, S, sm[w], ss[w]);
        const float logZ = M + logf(S);

        const int t  = target[row];
        const int tl = max(t - 1, 0);
        const int tr = min(t + 1, C - 1);
        const float pt = p[t];
        const float pl = p[tl];
        const float pr = p[tr];

        float wl, wr;
        if (t == 0)            { wl = 0.0f;           wr = SMOOTHING_F; }
        else if (t == C - 1)   { wl = SMOOTHING_F;    wr = 0.0f; }
        else                   { wl = 0.5f * SMOOTHING_F; wr = 0.5f * SMOOTHING_F; }

        // weights sum to 1 -> loss = logZ - (c*pt + wl*pl + wr*pr)
        row_loss[row] = logZ - (CONFIDENCE_F * pt + wl * pl + wr * pr);
    }
}

__global__ __launch_bounds__(256)
void reduce_mean_kernel(const float* __restrict__ row_loss,
                        float* __restrict__ out, int B) {
    float acc = 0.0f;
    for (int i = threadIdx.x; i < B; i += 256) acc += row_loss[i];
    #pragma unroll
    for (int i = 1; i < 64; i <<= 1) acc += __shfl_xor(acc, i, 64);
    __shared__ float sacc[4];
    const int wave = threadIdx.x >> 6;
    if ((threadIdx.x & 63) == 0) sacc[wave] = acc;
    __syncthreads();
    if (threadIdx.x == 0) {
        out[0] = (sacc[0] + sacc[1] + sacc[2] + sacc[3]) / (float)B;
    }
}

extern "C" void kernel_launch(void* const* d_in, const int* in_sizes, int n_in,
                              void* d_out, int out_size, void* d_ws, size_t ws_size,
                              hipStream_t stream) {
    const float* pred  = (const float*)d_in[0];
    const int* target  = (const int*)d_in[1];
    float* out         = (float*)d_out;
    float* row_loss    = (float*)d_ws;

    const int B = in_sizes[1];                 // 4096
    const int C = in_sizes[0] / in_sizes[1];   // 50257

    row_loss_kernel<<<B, 256, 0, stream>>>(pred, target, row_loss, C);
    reduce_mean_kernel<<<1, 256, 0, stream>>>(row_loss, out, B);
}